// Round 3
// baseline (2564.688 us; speedup 1.0000x reference)
//
#include <hip/hip_runtime.h>

// GRU-D fused recurrent kernel, fp32, one batch element per block (256 blocks x 512 thr).
// Thread map: wave wv (0..7), lane ln; h = wv*16 + (ln&15) in [0,128); q = ln>>4 in [0,4).
// Weights in registers: q-th 32-col slice of the x/m part and h(U) part of W_z/W_r/W_h rows,
// plus 16-col slice of W_gh. K-split partials reduced via shfl_xor(16/32).
// LDS vectors padded +4 floats per 32-float block => the 4 q-group b128 reads hit disjoint banks.

#define TSTEPS 512
#define DDIM   64
#define HDIM   128

__device__ __forceinline__ int physidx(int k) { return k + ((k >> 5) << 2); }

__device__ __forceinline__ float fast_sigmoid(float x) {
    return __fdividef(1.0f, 1.0f + __expf(-x));
}
__device__ __forceinline__ float fast_tanh(float x) {
    return fmaf(2.0f, fast_sigmoid(2.0f * x), -1.0f);
}

__device__ __forceinline__ void fma4(float& acc, const float4& wv_, const float4& vv_) {
    acc = fmaf(wv_.x, vv_.x, acc);
    acc = fmaf(wv_.y, vv_.y, acc);
    acc = fmaf(wv_.z, vv_.z, acc);
    acc = fmaf(wv_.w, vv_.w, acc);
}

__global__ __launch_bounds__(512) void grud_fused(
    const float* __restrict__ in,                                  // [B,4,T,64]
    const float* __restrict__ Wgx, const float* __restrict__ bgx,  // [64,64],[64]
    const float* __restrict__ Wgh, const float* __restrict__ bgh,  // [128,64],[128]
    const float* __restrict__ Wz,  const float* __restrict__ bz,   // [128,256],[128]
    const float* __restrict__ Wr,  const float* __restrict__ br,
    const float* __restrict__ Wh,  const float* __restrict__ bh,
    float* __restrict__ out)                                       // [B,T,128]
{
    const int tid = threadIdx.x;
    const int wv  = tid >> 6;
    const int ln  = tid & 63;
    const int h   = (wv << 4) | (ln & 15);
    const int q   = ln >> 4;
    const int b   = blockIdx.x;

    __shared__ __align__(16) float cvec[2][212];   // [x_t(64)|m(64)|d(64)] padded
    __shared__ __align__(16) float tmpx[2][64];
    __shared__ __align__(16) float tmpxl[2][64];
    __shared__ __align__(16) float hhbuf[140];     // decayed h, padded
    __shared__ __align__(16) float rhbuf[140];     // r*h, padded
    __shared__ __align__(16) float abuf[2][384];   // az|ar|ah (bias included)

    // column bases: q0->cols 0..31 (x), q1->32..63 (x), q2->192..223 (m), q3->224..255 (m)
    const int col0  = (q < 2) ? (q * 32) : (192 + (q - 2) * 32);
    const int ucol0 = 64 + q * 32;                        // h-part cols
    const int dbase = 144 + 16 * q + 4 * (q >> 1);        // phys base of d-slice q*16

    float4 wpz4[8], wpr4[8], wph4[8], uz4[8], ur4[8], uh4[8], wg4[4];
    {
        const float4* a0 = (const float4*)(Wz + h * 256 + col0);
        const float4* a1 = (const float4*)(Wr + h * 256 + col0);
        const float4* a2 = (const float4*)(Wh + h * 256 + col0);
        const float4* u0 = (const float4*)(Wz + h * 256 + ucol0);
        const float4* u1 = (const float4*)(Wr + h * 256 + ucol0);
        const float4* u2 = (const float4*)(Wh + h * 256 + ucol0);
#pragma unroll
        for (int i = 0; i < 8; ++i) {
            wpz4[i] = a0[i]; wpr4[i] = a1[i]; wph4[i] = a2[i];
            uz4[i]  = u0[i]; ur4[i]  = u1[i]; uh4[i]  = u2[i];
        }
        const float4* g0 = (const float4*)(Wgh + h * 64 + q * 16);
#pragma unroll
        for (int i = 0; i < 4; ++i) wg4[i] = g0[i];
    }
    const float bz_r = bz[h], br_r = br[h], bh_r = bh[h], bg_r = bgh[h];
    float wdiag = 0.f, bgx_r = 0.f;
    if (tid < 64) { wdiag = Wgx[tid * 65]; bgx_r = bgx[tid]; }

    if (tid < 128) hhbuf[physidx(tid)] = 0.f;
    float hhreg = 0.f;                       // this thread's hh[h] (decayed h)

    const int ch = tid >> 6;                 // channel for staging threads (tid<256)
    const int j  = tid & 63;
    const float* inp = in + (long)(((b << 2) + ch) * TSTEPS) * DDIM + j;

    float pre = 0.f;                         // holds raw(t+1) element
    // ---- prologue: stage raw(0), prefetch raw(1), compute x_t(0), abuf(0) ----
    if (tid < 256) {
        float v0 = inp[0];
        if (ch == 0)      tmpx[0][j] = v0;
        else if (ch == 1) tmpxl[0][j] = v0;
        else if (ch == 2) cvec[0][physidx(64 + j)] = v0;
        else              cvec[0][physidx(128 + j)] = v0;
        pre = inp[DDIM];
    }
    __syncthreads();
    if (tid < 64) {
        float m  = cvec[0][physidx(64 + j)];
        float d  = cvec[0][physidx(128 + j)];
        float dx = __expf(-fmaxf(fmaf(d, wdiag, bgx_r), 0.f));
        cvec[0][physidx(j)] = fmaf(m, tmpx[0][j], (1.f - m) * (dx * tmpxl[0][j]));
    }
    __syncthreads();
    {
        float pz = 0.f, pr = 0.f, ph = 0.f;
        const float4* cv4 = (const float4*)&cvec[0][q * 36];
#pragma unroll
        for (int i = 0; i < 8; ++i) {
            float4 cv = cv4[i];
            fma4(pz, wpz4[i], cv); fma4(pr, wpr4[i], cv); fma4(ph, wph4[i], cv);
        }
        pz += __shfl_xor(pz, 16); pz += __shfl_xor(pz, 32);
        pr += __shfl_xor(pr, 16); pr += __shfl_xor(pr, 32);
        ph += __shfl_xor(ph, 16); ph += __shfl_xor(ph, 32);
        if (ln < 16) {
            abuf[0][h]       = pz + bz_r;
            abuf[0][128 + h] = pr + br_r;
            abuf[0][256 + h] = ph + bh_r;
        }
        // delta_h(0)*h0 = 0, hhreg stays 0
    }
    __syncthreads();

    // ---- main loop: iteration t consumes (abuf[t&1], hh(t)), produces (abuf[(t+1)&1], hh(t+1)) ----
    for (int t = 0; t < TSTEPS; ++t) {
        const int cb = t & 1, nb = cb ^ 1;
        // seg1: stage raw(t+1) from prefetch reg; issue load raw(t+2); z/r U-matvec on hh(t)
        if (tid < 256) {
            if (ch == 0)      tmpx[nb][j] = pre;
            else if (ch == 1) tmpxl[nb][j] = pre;
            else if (ch == 2) cvec[nb][physidx(64 + j)] = pre;
            else              cvec[nb][physidx(128 + j)] = pre;
            int tl = t + 2; tl = (tl < TSTEPS) ? tl : (TSTEPS - 1);
            pre = inp[(long)tl * DDIM];
        }
        float za = 0.f, ra = 0.f;
        {
            const float4* hv4 = (const float4*)&hhbuf[q * 36];
#pragma unroll
            for (int i = 0; i < 8; ++i) {
                float4 hv = hv4[i];
                fma4(za, uz4[i], hv); fma4(ra, ur4[i], hv);
            }
        }
        __syncthreads();   // alpha: raw(t+1) staged visible; hh reads done
        // seg2: x_t(t+1); finish z,r; write r*hh
        if (tid < 64) {
            float m  = cvec[nb][physidx(64 + j)];
            float d  = cvec[nb][physidx(128 + j)];
            float dx = __expf(-fmaxf(fmaf(d, wdiag, bgx_r), 0.f));
            cvec[nb][physidx(j)] = fmaf(m, tmpx[nb][j], (1.f - m) * (dx * tmpxl[nb][j]));
        }
        za += __shfl_xor(za, 16); za += __shfl_xor(za, 32);
        ra += __shfl_xor(ra, 16); ra += __shfl_xor(ra, 32);
        float z    = fast_sigmoid(abuf[cb][h] + za);
        float r    = fast_sigmoid(abuf[cb][128 + h] + ra);
        float ah_v = abuf[cb][256 + h];
        if (ln < 16) rhbuf[physidx(h)] = r * hhreg;
        __syncthreads();   // beta: rh + x_t(t+1) visible
        // seg3: h~ matvec; input matvec for t+1; state update + output
        float ha = 0.f;
        {
            const float4* rv4 = (const float4*)&rhbuf[q * 36];
#pragma unroll
            for (int i = 0; i < 8; ++i) { float4 rv = rv4[i]; fma4(ha, uh4[i], rv); }
        }
        float pz = 0.f, pr = 0.f, ph = 0.f, pg = 0.f;
        {
            const float4* cv4 = (const float4*)&cvec[nb][q * 36];
#pragma unroll
            for (int i = 0; i < 8; ++i) {
                float4 cv = cv4[i];
                fma4(pz, wpz4[i], cv); fma4(pr, wpr4[i], cv); fma4(ph, wph4[i], cv);
            }
            const float4* dv4 = (const float4*)&cvec[nb][dbase];
#pragma unroll
            for (int i = 0; i < 4; ++i) { float4 dv = dv4[i]; fma4(pg, wg4[i], dv); }
        }
        ha += __shfl_xor(ha, 16); ha += __shfl_xor(ha, 32);
        pz += __shfl_xor(pz, 16); pz += __shfl_xor(pz, 32);
        pr += __shfl_xor(pr, 16); pr += __shfl_xor(pr, 32);
        ph += __shfl_xor(ph, 16); ph += __shfl_xor(ph, 32);
        pg += __shfl_xor(pg, 16); pg += __shfl_xor(pg, 32);
        float htv  = fast_tanh(ah_v + ha);
        float hnew = fmaf(z, htv - hhreg, hhreg);            // (1-z)*hh + z*h~
        hhreg = __expf(-fmaxf(pg + bg_r, 0.f)) * hnew;       // hh(t+1) = delta_h(t+1)*h(t)
        if (ln < 16) {
            out[(((b * TSTEPS) + t) << 7) + h] = hnew;
            hhbuf[physidx(h)] = hhreg;
            abuf[nb][h]       = pz + bz_r;
            abuf[nb][128 + h] = pr + br_r;
            abuf[nb][256 + h] = ph + bh_r;
        }
        __syncthreads();   // gamma: hh(t+1), abuf(t+1) visible
    }
}

extern "C" void kernel_launch(void* const* d_in, const int* in_sizes, int n_in,
                              void* d_out, int out_size, void* d_ws, size_t ws_size,
                              hipStream_t stream) {
    const float* in  = (const float*)d_in[0];
    const float* Wgx = (const float*)d_in[1];
    const float* bgx = (const float*)d_in[2];
    const float* Wgh = (const float*)d_in[3];
    const float* bgh = (const float*)d_in[4];
    const float* Wz  = (const float*)d_in[5];
    const float* bz  = (const float*)d_in[6];
    const float* Wr  = (const float*)d_in[7];
    const float* br  = (const float*)d_in[8];
    const float* Wh  = (const float*)d_in[9];
    const float* bh  = (const float*)d_in[10];
    grud_fused<<<256, 512, 0, stream>>>(in, Wgx, bgx, Wgh, bgh, Wz, bz, Wr, br, Wh, bh,
                                        (float*)d_out);
}